// Round 1
// baseline (240.593 us; speedup 1.0000x reference)
//
#include <hip/hip_runtime.h>

// Problem: RetrievalHeadPyramidBottomUpInstantSimple
// feat0 [32,256,56,56], feat1 [32,512,28,28], feat2 [32,1024,14,14],
// feat3 [32,2048,7,7], conv_w [1024,3840]  (all fp32)
// out [32,1024] fp32.
//
// Key identity (verified analytically against jax.image.resize 'bilinear'
// half-pixel weights incl. edge normalization): for integer upsample factors
// 1/2/4/8 to 56x56, the per-input-pixel weight column sums are exactly
// uniform, so mean(upsample(f)) == mean(f). Hence:
//   out = concat_l(spatial_mean(feat_l)) @ conv_w^T

#define NPLANES0 8192    // 32*256, 3136 el each
#define NPLANES1 16384   // 32*512, 784 el
#define NPLANES2 32768   // 32*1024, 196 el
#define NPLANES3 65536   // 32*2048, 49 el
#define TOTAL_PLANES 122880

__global__ __launch_bounds__(256) void pool_kernel(
    const float* __restrict__ f0, const float* __restrict__ f1,
    const float* __restrict__ f2, const float* __restrict__ f3,
    float* __restrict__ v)
{
    int wid  = (blockIdx.x << 2) + (threadIdx.x >> 6);  // wave id = plane id
    int lane = threadIdx.x & 63;
    float s = 0.f;
    int b, col;
    float inv;
    if (wid < NPLANES0) {
        int q = wid;
        const float4* p = (const float4*)(f0 + (size_t)q * 3136);  // 784 f4
        #pragma unroll
        for (int t = 0; t < 12; ++t) {
            float4 x = p[lane + (t << 6)];
            s += x.x + x.y + x.z + x.w;
        }
        if (lane < 16) { float4 x = p[768 + lane]; s += x.x + x.y + x.z + x.w; }
        b = q >> 8; col = q & 255; inv = 1.f / 3136.f;
    } else if (wid < NPLANES0 + NPLANES1) {
        int q = wid - NPLANES0;
        const float4* p = (const float4*)(f1 + (size_t)q * 784);   // 196 f4
        #pragma unroll
        for (int t = 0; t < 3; ++t) {
            float4 x = p[lane + (t << 6)];
            s += x.x + x.y + x.z + x.w;
        }
        if (lane < 4) { float4 x = p[192 + lane]; s += x.x + x.y + x.z + x.w; }
        b = q >> 9; col = 256 + (q & 511); inv = 1.f / 784.f;
    } else if (wid < NPLANES0 + NPLANES1 + NPLANES2) {
        int q = wid - (NPLANES0 + NPLANES1);
        const float4* p = (const float4*)(f2 + (size_t)q * 196);   // 49 f4
        if (lane < 49) { float4 x = p[lane]; s += x.x + x.y + x.z + x.w; }
        b = q >> 10; col = 768 + (q & 1023); inv = 1.f / 196.f;
    } else {
        int q = wid - (NPLANES0 + NPLANES1 + NPLANES2);
        const float* p = f3 + (size_t)q * 49;                      // 49 floats
        if (lane < 49) s = p[lane];
        b = q >> 11; col = 1792 + (q & 2047); inv = 1.f / 49.f;
    }
    // wave-64 butterfly reduction
    #pragma unroll
    for (int off = 32; off >= 1; off >>= 1) s += __shfl_xor(s, off);
    if (lane == 0) v[b * 3840 + col] = s * inv;
}

// GEMM: out[b,e] = sum_k v[b,k] * W[e,k];  M=32, N=1024, K=3840
// Split-K x32 (chunks of 120), e-tile 128 per block -> grid 256 blocks.
// Block = 256 threads = (8 b-groups x 32 e-lanes), thread tile 4b x 4e.
#define KT 120
#define LDP 124  // padded LDS stride (floats), 16B-aligned, breaks pow2 banks

__global__ __launch_bounds__(256) void gemm_kernel(
    const float* __restrict__ v, const float* __restrict__ W,
    float* __restrict__ partials)
{
    __shared__ float vs[32][LDP];
    __shared__ float ws[128][LDP];
    int t  = threadIdx.x;
    int et = blockIdx.x & 7;
    int ks = blockIdx.x >> 3;
    int e0 = et << 7;        // 0..896
    int k0 = ks * KT;        // 0..3720

    // stage v tile: 32x120 = 960 float4
    #pragma unroll
    for (int j = 0; j < 4; ++j) {
        int f = t + (j << 8);
        if (f < 960) {
            int row = f / 30, c4 = f % 30;
            *(float4*)&vs[row][c4 * 4] =
                *(const float4*)&v[row * 3840 + k0 + c4 * 4];
        }
    }
    // stage W tile: 128x120 = 3840 float4 (15 per thread exactly)
    #pragma unroll
    for (int j = 0; j < 15; ++j) {
        int f = t + (j << 8);
        int row = f / 30, c4 = f % 30;
        *(float4*)&ws[row][c4 * 4] =
            *(const float4*)&W[(size_t)(e0 + row) * 3840 + k0 + c4 * 4];
    }
    __syncthreads();

    int bg = t >> 5, eg = t & 31;
    int b0 = bg << 2;
    float acc[4][4] = {};
    #pragma unroll 6
    for (int k = 0; k < KT; k += 4) {
        float4 vv[4], ww[4];
        #pragma unroll
        for (int i = 0; i < 4; ++i) vv[i] = *(const float4*)&vs[b0 + i][k];
        #pragma unroll
        for (int j = 0; j < 4; ++j) ww[j] = *(const float4*)&ws[eg + (j << 5)][k];
        #pragma unroll
        for (int i = 0; i < 4; ++i)
            #pragma unroll
            for (int j = 0; j < 4; ++j)
                acc[i][j] += vv[i].x * ww[j].x + vv[i].y * ww[j].y +
                             vv[i].z * ww[j].z + vv[i].w * ww[j].w;
    }

    float* pout = partials + (size_t)ks * 32768;
    #pragma unroll
    for (int i = 0; i < 4; ++i)
        #pragma unroll
        for (int j = 0; j < 4; ++j)
            pout[(b0 + i) * 1024 + e0 + eg + (j << 5)] = acc[i][j];
}

__global__ __launch_bounds__(256) void reduce_kernel(
    const float* __restrict__ partials, float* __restrict__ out)
{
    int idx = blockIdx.x * 256 + threadIdx.x;  // 0..32767 = b*1024+e
    float s = 0.f;
    #pragma unroll
    for (int ksp = 0; ksp < 32; ++ksp) s += partials[ksp * 32768 + idx];
    out[idx] = s;
}

extern "C" void kernel_launch(void* const* d_in, const int* in_sizes, int n_in,
                              void* d_out, int out_size, void* d_ws, size_t ws_size,
                              hipStream_t stream)
{
    const float* f0 = (const float*)d_in[0];
    const float* f1 = (const float*)d_in[1];
    const float* f2 = (const float*)d_in[2];
    const float* f3 = (const float*)d_in[3];
    const float* W  = (const float*)d_in[4];
    float* out = (float*)d_out;

    float* v        = (float*)d_ws;          // 32*3840  = 122880 floats
    float* partials = v + 32 * 3840;         // 32*32768 = 1048576 floats

    pool_kernel<<<TOTAL_PLANES / 4, 256, 0, stream>>>(f0, f1, f2, f3, v);
    gemm_kernel<<<256, 256, 0, stream>>>(v, W, partials);
    reduce_kernel<<<32768 / 256, 256, 0, stream>>>(partials, out);
}

// Round 3
// 233.744 us; speedup vs baseline: 1.0293x; 1.0293x over previous
//
#include <hip/hip_runtime.h>

// RetrievalHeadPyramidBottomUpInstantSimple
// feat0 [32,256,56,56], feat1 [32,512,28,28], feat2 [32,1024,14,14],
// feat3 [32,2048,7,7], conv_w [1024,3840]  (all fp32) -> out [32,1024] fp32
//
// Identity: jax bilinear half-pixel upsample by integer factor to 56x56 has
// exactly-uniform per-input-pixel weight column sums, so
// mean(upsample(f)) == mean(f).  Hence:
//   out = concat_l(spatial_mean(feat_l)) @ conv_w^T
//
// R2 bug: f1/f2/f3 LDS staging covered only 768 of 784 float4 (the
// `t < 272` guard assumed 512 threads). Fixed: 3 full rounds + t<16 tail.

__global__ __launch_bounds__(256) void pool_kernel(
    const float* __restrict__ f0, const float* __restrict__ f1,
    const float* __restrict__ f2, const float* __restrict__ f3,
    float* __restrict__ v)
{
    __shared__ float l[3136];   // 12.5 KB
    int bid = blockIdx.x;
    int t = threadIdx.x;

    if (bid < 8192) {
        // ---- f0: one block per plane (3136 floats = 784 float4) ----
        const float4* p = (const float4*)(f0 + (size_t)bid * 3136);
        float4 a = p[t], b2 = p[t + 256], c = p[t + 512];
        float s = a.x + a.y + a.z + a.w
                + b2.x + b2.y + b2.z + b2.w
                + c.x + c.y + c.z + c.w;
        if (t < 16) { float4 d = p[t + 768]; s += d.x + d.y + d.z + d.w; }
        #pragma unroll
        for (int o = 32; o; o >>= 1) s += __shfl_xor(s, o);
        if ((t & 63) == 0) l[t >> 6] = s;
        __syncthreads();
        if (t == 0)
            v[(bid >> 8) * 3840 + (bid & 255)] =
                (l[0] + l[1] + l[2] + l[3]) * (1.f / 3136.f);
        return;
    }

    float4* lf = (float4*)l;
    if (bid < 12288) {
        // ---- f1: one block per 4 planes (4 x 784 floats = 784 float4) ----
        int blk = bid - 8192;
        const float4* src = (const float4*)(f1 + (size_t)blk * 3136);
        lf[t] = src[t]; lf[t + 256] = src[t + 256]; lf[t + 512] = src[t + 512];
        if (t < 16) lf[t + 768] = src[t + 768];
        __syncthreads();
        int w = t >> 6, lane = t & 63;
        const float* base = l + w * 784;
        float s = 0.f;
        #pragma unroll
        for (int i = 0; i < 12; ++i) s += base[lane + (i << 6)];
        if (lane < 16) s += base[768 + lane];
        #pragma unroll
        for (int o = 32; o; o >>= 1) s += __shfl_xor(s, o);
        if (lane == 0) {
            int q = blk * 4 + w;
            v[(q >> 9) * 3840 + 256 + (q & 511)] = s * (1.f / 784.f);
        }
    } else if (bid < 14336) {
        // ---- f2: one block per 16 planes (16 x 196 floats) ----
        int blk = bid - 12288;
        const float4* src = (const float4*)(f2 + (size_t)blk * 3136);
        lf[t] = src[t]; lf[t + 256] = src[t + 256]; lf[t + 512] = src[t + 512];
        if (t < 16) lf[t + 768] = src[t + 768];
        __syncthreads();
        int p = t >> 4, j = t & 15;
        const float* base = l + p * 196;
        float s = 0.f;
        #pragma unroll
        for (int i = 0; i < 12; ++i) s += base[j + (i << 4)];
        if (j < 4) s += base[192 + j];
        s += __shfl_xor(s, 8); s += __shfl_xor(s, 4);
        s += __shfl_xor(s, 2); s += __shfl_xor(s, 1);
        if (j == 0) {
            int q = blk * 16 + p;
            v[(q >> 10) * 3840 + 768 + (q & 1023)] = s * (1.f / 196.f);
        }
    } else {
        // ---- f3: one block per 64 planes (64 x 49 floats) ----
        int blk = bid - 14336;
        const float4* src = (const float4*)(f3 + (size_t)blk * 3136);
        lf[t] = src[t]; lf[t + 256] = src[t + 256]; lf[t + 512] = src[t + 512];
        if (t < 16) lf[t + 768] = src[t + 768];
        __syncthreads();
        int p = t >> 2, j = t & 3;
        const float* base = l + p * 49;
        float s = 0.f;
        #pragma unroll
        for (int i = 0; i < 12; ++i) s += base[j + (i << 2)];
        if (j == 0) s += base[48];
        s += __shfl_xor(s, 2); s += __shfl_xor(s, 1);
        if (j == 0) {
            int q = blk * 64 + p;
            v[(q >> 11) * 3840 + 1792 + (q & 2047)] = s * (1.f / 49.f);
        }
    }
}

// GEMM: out[b,e] = sum_k v[b,k]*W[e,k]; M=32,N=1024,K=3840
// e-tile 64, split-K x32 (KT=120) -> grid 16*32=512 blocks (2 blocks/CU).
#define KT 120

__global__ __launch_bounds__(256) void gemm_kernel(
    const float* __restrict__ v, const float* __restrict__ W,
    float* __restrict__ partials)
{
    __shared__ float vs[32][124];
    __shared__ float wsh[64][124];
    int t = threadIdx.x;
    int et = blockIdx.x & 15, ks = blockIdx.x >> 4;
    int e0 = et << 6, k0 = ks * KT;

    // stage v tile: 32 rows x 30 f4 = 960 f4
    {
        int f = t;
        #pragma unroll
        for (int i = 0; i < 3; ++i, f += 256) {
            int row = f / 30, c4 = f % 30;
            *(float4*)&vs[row][c4 * 4] =
                *(const float4*)&v[row * 3840 + k0 + c4 * 4];
        }
        if (t < 192) {
            f = t + 768;
            int row = f / 30, c4 = f % 30;
            *(float4*)&vs[row][c4 * 4] =
                *(const float4*)&v[row * 3840 + k0 + c4 * 4];
        }
    }
    // stage W tile: 64 rows x 30 f4 = 1920 f4
    {
        int f = t;
        #pragma unroll
        for (int i = 0; i < 7; ++i, f += 256) {
            int row = f / 30, c4 = f % 30;
            *(float4*)&wsh[row][c4 * 4] =
                *(const float4*)&W[(size_t)(e0 + row) * 3840 + k0 + c4 * 4];
        }
        if (t < 128) {
            f = t + 1792;
            int row = f / 30, c4 = f % 30;
            *(float4*)&wsh[row][c4 * 4] =
                *(const float4*)&W[(size_t)(e0 + row) * 3840 + k0 + c4 * 4];
        }
    }
    __syncthreads();

    int bg = t >> 5, eg = t & 31;
    int b0 = bg << 2;
    float acc[4][2] = {};
    #pragma unroll 5
    for (int k = 0; k < KT; k += 4) {
        float4 vv[4], ww[2];
        #pragma unroll
        for (int i = 0; i < 4; ++i) vv[i] = *(const float4*)&vs[b0 + i][k];
        #pragma unroll
        for (int j = 0; j < 2; ++j) ww[j] = *(const float4*)&wsh[eg + (j << 5)][k];
        #pragma unroll
        for (int i = 0; i < 4; ++i)
            #pragma unroll
            for (int j = 0; j < 2; ++j)
                acc[i][j] += vv[i].x * ww[j].x + vv[i].y * ww[j].y +
                             vv[i].z * ww[j].z + vv[i].w * ww[j].w;
    }

    float* pout = partials + (size_t)ks * 32768 + (size_t)b0 * 1024 + e0 + eg;
    #pragma unroll
    for (int i = 0; i < 4; ++i)
        #pragma unroll
        for (int j = 0; j < 2; ++j)
            pout[i * 1024 + (j << 5)] = acc[i][j];
}

__global__ __launch_bounds__(256) void reduce_kernel(
    const float* __restrict__ partials, float* __restrict__ out)
{
    int idx = blockIdx.x * 256 + threadIdx.x;  // 0..32767
    float s = 0.f;
    #pragma unroll
    for (int sp = 0; sp < 32; ++sp) s += partials[sp * 32768 + idx];
    out[idx] = s;
}

extern "C" void kernel_launch(void* const* d_in, const int* in_sizes, int n_in,
                              void* d_out, int out_size, void* d_ws, size_t ws_size,
                              hipStream_t stream)
{
    const float* f0 = (const float*)d_in[0];
    const float* f1 = (const float*)d_in[1];
    const float* f2 = (const float*)d_in[2];
    const float* f3 = (const float*)d_in[3];
    const float* W  = (const float*)d_in[4];
    float* out = (float*)d_out;

    float* v        = (float*)d_ws;      // 32*3840 floats
    float* partials = v + 32 * 3840;     // 32*32768 floats = 4 MB

    pool_kernel<<<15360, 256, 0, stream>>>(f0, f1, f2, f3, v);
    gemm_kernel<<<512, 256, 0, stream>>>(v, W, partials);
    reduce_kernel<<<128, 256, 0, stream>>>(partials, out);
}